// Round 1
// baseline (675.153 us; speedup 1.0000x reference)
//
#include <hip/hip_runtime.h>

// LSTM forward scan: T=1024, B=16, NH=12, HD=64, NG=4 (i,f,z,o).
// One block per (b,n) chain: 192 blocks x 256 threads; tid = o*4+g.
//
// Round-2 lessons (kept):
//  * 16 NAMED float4 scalars for R — arrays defeat SROA -> scratch.
//  * raw `s_waitcnt lgkmcnt(0); s_barrier` — __syncthreads() drains vmcnt(0)
//    and kills the Wx prefetch ring.
// Round-3 changes (this round):
//  * gate exchange via DPP quad_perm (VALU) instead of ds_swizzle (LDS pipe):
//    xor1/2/3 are intra-quad -> v_mov_b32_dpp, no lgkmcnt on the critical tail.
//  * g==1 lanes compute a VALID c via a 4-cndmask operand swap
//    (gates[j]=vals[j^g]); h and c then store straight from registers
//    (g==0 -> h plane, g==1 -> c plane). Removes the 128 post-barrier
//    ds_read_b32 per step and drops c from the LDS handoff.

#define T_SEQ 1024
#define B_    16
#define NH_   12
#define HD_   64
#define NG_   4
#define BN_   (B_*NH_)                    // 192 chains
#define WX_T_STRIDE (BN_*HD_*NG_)         // 49152 floats per timestep
#define OUT_T_STRIDE (BN_*HD_)            // 12288 floats per timestep
#define OUT_S_STRIDE ((T_SEQ+1)*OUT_T_STRIDE)

// raw workgroup barrier: orders LDS (lgkmcnt) but does NOT drain vmcnt —
// keeps the global prefetch ring in flight across steps.
#define LDS_BARRIER() asm volatile("s_waitcnt lgkmcnt(0)\n\ts_barrier" ::: "memory")

// intra-quad lane exchange via DPP quad_perm — pure VALU, no LDS pipe.
// 0xB1 = [1,0,3,2] (xor1), 0x4E = [2,3,0,1] (xor2), 0x1B = [3,2,1,0] (xor3)
#define QXOR(x, CTRL) \
    __int_as_float(__builtin_amdgcn_update_dpp(0, __float_as_int(x), (CTRL), 0xF, 0xF, true))

__global__ __launch_bounds__(256, 1) __attribute__((amdgpu_waves_per_eu(1)))
void flashrnn_lstm_fwd(const float* __restrict__ Wx,
                       const float* __restrict__ s0,
                       const float* __restrict__ R,
                       const float* __restrict__ bias,
                       float* __restrict__ out)
{
    const int bid = blockIdx.x;           // 0..191
    const int n   = bid % NH_;
    const int b   = bid / NH_;
    const int bn  = b*NH_ + n;
    const int tid = threadIdx.x;          // 0..255
    const int o   = tid >> 2;             // output index 0..63
    const int g   = tid & 3;              // gate 0..3 (i,f,z,o)

    __shared__ float hbuf[2][64];         // h only — c never goes through LDS

    // --- R row R[n][g][o][0:64] into 16 NAMED float4 registers ---
    const float4* Rp = (const float4*)(R + ((size_t)((n*NG_ + g)*HD_ + o)) * HD_);
    float4 r0 = Rp[0],  r1 = Rp[1],  r2 = Rp[2],  r3 = Rp[3];
    float4 r4 = Rp[4],  r5 = Rp[5],  r6 = Rp[6],  r7 = Rp[7];
    float4 r8 = Rp[8],  r9 = Rp[9],  r10 = Rp[10], r11 = Rp[11];
    float4 r12 = Rp[12], r13 = Rp[13], r14 = Rp[14], r15 = Rp[15];

    const float bval = bias[(n*NG_ + g)*HD_ + o];

    // c state is valid in g==0 AND g==1 lanes (operand-swap below)
    float c = s0[BN_*HD_ + bn*HD_ + o];

    // --- init h in LDS buf 0 + write t=0 output slices ---
    if (tid < 128) {
        const int d = tid & 63;
        const size_t sofs = (tid < 64) ? (size_t)0 : (size_t)OUT_S_STRIDE;
        const float v = (tid < 64) ? s0[bn*HD_ + d] : s0[BN_*HD_ + bn*HD_ + d];
        if (tid < 64) hbuf[0][d] = v;
        out[sofs + (size_t)bn*HD_ + d] = v;                           // t = 0
    }

    // per-lane store pointer: g==0 -> h plane, g==1 -> c plane, at t=1
    const bool isg1 = (g & 1) != 0;
    float* stp = out + (isg1 ? (size_t)OUT_S_STRIDE : (size_t)0)
                     + (size_t)OUT_T_STRIDE + (size_t)bn*HD_ + o;

    // unified activation: a = m * rcp(1 + exp2(s*x)) + k
    // g in {0,1,3}: sigmoid; g==2: tanh
    const float s_coef = (g == 2) ? -2.88539008f : -1.44269504f;
    const float m_coef = (g == 2) ? 2.0f : 1.0f;
    const float a_coef = (g == 2) ? -1.0f : 0.0f;

    // --- Wx prefetch ring (depth 4), named scalars ---
    const float* wxp = Wx + (size_t)bn*(HD_*NG_) + tid;
    float wx0 = wxp[0];
    float wx1 = wxp[(size_t)1 * WX_T_STRIDE];
    float wx2 = wxp[(size_t)2 * WX_T_STRIDE];
    float wx3 = wxp[(size_t)3 * WX_T_STRIDE];

    __syncthreads();   // one full barrier before the loop (drains init loads)

#define DOT(R4, H4)                                                            \
        acc.x = fmaf((R4).x, (H4).x, acc.x);                                   \
        acc.y = fmaf((R4).y, (H4).y, acc.y);                                   \
        acc.z = fmaf((R4).z, (H4).z, acc.z);                                   \
        acc.w = fmaf((R4).w, (H4).w, acc.w);

#define STEP(TT, SLOT, CUR)                                                    \
    {                                                                          \
        const float wxv = wx##SLOT;                                            \
        { int tl = tb + (TT) + 4; if (tl > T_SEQ-1) tl = T_SEQ-1;              \
          wx##SLOT = wxp[(size_t)tl * WX_T_STRIDE]; }                          \
        float4 acc = make_float4(0.f, 0.f, 0.f, 0.f);                          \
        const float4* hv = (const float4*)&hbuf[CUR][0];                       \
        const float4 h0 = hv[0],  h1 = hv[1],  h2 = hv[2],  h3 = hv[3];        \
        const float4 h4 = hv[4],  h5 = hv[5],  h6 = hv[6],  h7 = hv[7];        \
        const float4 h8 = hv[8],  h9 = hv[9],  h10 = hv[10], h11 = hv[11];     \
        const float4 h12 = hv[12], h13 = hv[13], h14 = hv[14], h15 = hv[15];   \
        DOT(r0,h0)  DOT(r1,h1)  DOT(r2,h2)  DOT(r3,h3)                         \
        DOT(r4,h4)  DOT(r5,h5)  DOT(r6,h6)  DOT(r7,h7)                         \
        DOT(r8,h8)  DOT(r9,h9)  DOT(r10,h10) DOT(r11,h11)                      \
        DOT(r12,h12) DOT(r13,h13) DOT(r14,h14) DOT(r15,h15)                    \
        const float gp = ((acc.x+acc.y)+(acc.z+acc.w)) + wxv + bval;           \
        const float ev = __builtin_amdgcn_exp2f(s_coef * gp);                  \
        const float rv = __builtin_amdgcn_rcpf(1.0f + ev);                     \
        const float a  = fmaf(m_coef, rv, a_coef);                             \
        const float v1 = QXOR(a, 0xB1);  /* gate g^1 */                        \
        const float v2 = QXOR(a, 0x4E);  /* gate g^2 */                        \
        const float v3 = QXOR(a, 0x1B);  /* gate g^3 */                        \
        /* gates[j] = vals[j^g]; valid for g==0 AND g==1 via one-bit select */ \
        const float xf = isg1 ? a  : v1;                                       \
        const float xi = isg1 ? v1 : a;                                        \
        const float xz = isg1 ? v3 : v2;                                       \
        const float xo = isg1 ? v2 : v3;                                       \
        c = fmaf(xf, c, xi * xz);                                              \
        const float e2 = __builtin_amdgcn_exp2f(-2.88539008f * c);             \
        const float th = fmaf(2.0f, __builtin_amdgcn_rcpf(1.0f + e2), -1.0f);  \
        const float hval = xo * th;                                            \
        if (g == 0) hbuf[(CUR)^1][o] = hval;                                   \
        if (g < 2) { *stp = isg1 ? c : hval; stp += OUT_T_STRIDE; }            \
        LDS_BARRIER();                                                         \
    }

    for (int tb = 0; tb < T_SEQ; tb += 4) {
        STEP(0, 0, 0)
        STEP(1, 1, 1)
        STEP(2, 2, 0)
        STEP(3, 3, 1)
    }
#undef STEP
#undef DOT
}

extern "C" void kernel_launch(void* const* d_in, const int* in_sizes, int n_in,
                              void* d_out, int out_size, void* d_ws, size_t ws_size,
                              hipStream_t stream) {
    const float* Wx = (const float*)d_in[0];
    const float* s0 = (const float*)d_in[1];
    const float* R  = (const float*)d_in[2];
    const float* bb = (const float*)d_in[3];
    float* out = (float*)d_out;
    flashrnn_lstm_fwd<<<dim3(BN_), dim3(256), 0, stream>>>(Wx, s0, R, bb, out);
}

// Round 2
// 673.582 us; speedup vs baseline: 1.0023x; 1.0023x over previous
//
#include <hip/hip_runtime.h>

// LSTM forward scan: T=1024, B=16, NH=12, HD=64, NG=4 (i,f,z,o).
// One block per (b,n) chain: 192 blocks x 256 threads; tid = o*4+g.
//
// Lessons carried:
//  * raw `s_waitcnt lgkmcnt(0); s_barrier` — __syncthreads() drains vmcnt(0)
//    and kills the Wx prefetch ring.
//  * DPP quad_perm for the gate exchange (VALU, not LDS pipe).
//  * h and c stored to out straight from registers (g==0/g==1 lanes).
// Round-4 fix (this round):
//  * VGPR_Count=48 proved R was NOT register-resident: the per-step barrier's
//    `::: "memory"` clobber invalidates every memory-derived value, so the
//    compiler re-loaded all 64 R floats from L2 each step (~27 TB/s of L2
//    traffic, ~79% of ceiling — the real bottleneck; VALUBusy 27%).
//    Fix: launder R (and bval) through `asm volatile("" : "+v"(x))` once
//    after loading. The values become asm outputs, not memory loads, so the
//    memory clobber can't force a reload — R stays pinned in VGPRs.
//    ext_vector_type(4) floats pin as one 128-bit "v" tuple (no alloca/SROA
//    trap, same idiom as MFMA inline asm).

#define T_SEQ 1024
#define B_    16
#define NH_   12
#define HD_   64
#define NG_   4
#define BN_   (B_*NH_)                    // 192 chains
#define WX_T_STRIDE (BN_*HD_*NG_)         // 49152 floats per timestep
#define OUT_T_STRIDE (BN_*HD_)            // 12288 floats per timestep
#define OUT_S_STRIDE ((T_SEQ+1)*OUT_T_STRIDE)

typedef float v4f __attribute__((ext_vector_type(4)));

// raw workgroup barrier: orders LDS (lgkmcnt) but does NOT drain vmcnt —
// keeps the global prefetch ring in flight across steps.
#define LDS_BARRIER() asm volatile("s_waitcnt lgkmcnt(0)\n\ts_barrier" ::: "memory")

// pin a 128-bit value into VGPRs: value becomes an asm output, immune to
// "memory"-clobber-induced reloads.
#define PIN4(x) asm volatile("" : "+v"(x))
#define PIN1(x) asm volatile("" : "+v"(x))

// intra-quad lane exchange via DPP quad_perm — pure VALU, no LDS pipe.
// 0xB1 = [1,0,3,2] (xor1), 0x4E = [2,3,0,1] (xor2), 0x1B = [3,2,1,0] (xor3)
#define QXOR(x, CTRL) \
    __int_as_float(__builtin_amdgcn_update_dpp(0, __float_as_int(x), (CTRL), 0xF, 0xF, true))

__global__ __launch_bounds__(256, 1) __attribute__((amdgpu_waves_per_eu(1)))
void flashrnn_lstm_fwd(const float* __restrict__ Wx,
                       const float* __restrict__ s0,
                       const float* __restrict__ R,
                       const float* __restrict__ bias,
                       float* __restrict__ out)
{
    const int bid = blockIdx.x;           // 0..191
    const int n   = bid % NH_;
    const int b   = bid / NH_;
    const int bn  = b*NH_ + n;
    const int tid = threadIdx.x;          // 0..255
    const int o   = tid >> 2;             // output index 0..63
    const int g   = tid & 3;              // gate 0..3 (i,f,z,o)

    __shared__ float hbuf[2][64];         // h only — c never goes through LDS

    // --- R row R[n][g][o][0:64] into 16 named 128-bit registers, pinned ---
    const v4f* Rp = (const v4f*)(R + ((size_t)((n*NG_ + g)*HD_ + o)) * HD_);
    v4f r0 = Rp[0],  r1 = Rp[1],  r2 = Rp[2],  r3 = Rp[3];
    v4f r4 = Rp[4],  r5 = Rp[5],  r6 = Rp[6],  r7 = Rp[7];
    v4f r8 = Rp[8],  r9 = Rp[9],  r10 = Rp[10], r11 = Rp[11];
    v4f r12 = Rp[12], r13 = Rp[13], r14 = Rp[14], r15 = Rp[15];
    PIN4(r0);  PIN4(r1);  PIN4(r2);  PIN4(r3);
    PIN4(r4);  PIN4(r5);  PIN4(r6);  PIN4(r7);
    PIN4(r8);  PIN4(r9);  PIN4(r10); PIN4(r11);
    PIN4(r12); PIN4(r13); PIN4(r14); PIN4(r15);

    float bval = bias[(n*NG_ + g)*HD_ + o];
    PIN1(bval);

    // c state is valid in g==0 AND g==1 lanes (operand-swap below)
    float c = s0[BN_*HD_ + bn*HD_ + o];

    // --- init h in LDS buf 0 + write t=0 output slices ---
    if (tid < 128) {
        const int d = tid & 63;
        const size_t sofs = (tid < 64) ? (size_t)0 : (size_t)OUT_S_STRIDE;
        const float v = (tid < 64) ? s0[bn*HD_ + d] : s0[BN_*HD_ + bn*HD_ + d];
        if (tid < 64) hbuf[0][d] = v;
        out[sofs + (size_t)bn*HD_ + d] = v;                           // t = 0
    }

    // per-lane store pointer: g==0 -> h plane, g==1 -> c plane, at t=1
    const bool isg1 = (g & 1) != 0;
    float* stp = out + (isg1 ? (size_t)OUT_S_STRIDE : (size_t)0)
                     + (size_t)OUT_T_STRIDE + (size_t)bn*HD_ + o;

    // unified activation: a = m * rcp(1 + exp2(s*x)) + k
    // g in {0,1,3}: sigmoid; g==2: tanh
    const float s_coef = (g == 2) ? -2.88539008f : -1.44269504f;
    const float m_coef = (g == 2) ? 2.0f : 1.0f;
    const float a_coef = (g == 2) ? -1.0f : 0.0f;

    // --- Wx prefetch ring (depth 4), named scalars ---
    const float* wxp = Wx + (size_t)bn*(HD_*NG_) + tid;
    float wx0 = wxp[0];
    float wx1 = wxp[(size_t)1 * WX_T_STRIDE];
    float wx2 = wxp[(size_t)2 * WX_T_STRIDE];
    float wx3 = wxp[(size_t)3 * WX_T_STRIDE];

    __syncthreads();   // one full barrier before the loop (drains init loads)

#define DOT(R4, H4)                                                            \
        acc.x = fmaf((R4).x, (H4).x, acc.x);                                   \
        acc.y = fmaf((R4).y, (H4).y, acc.y);                                   \
        acc.z = fmaf((R4).z, (H4).z, acc.z);                                   \
        acc.w = fmaf((R4).w, (H4).w, acc.w);

#define STEP(TT, SLOT, CUR)                                                    \
    {                                                                          \
        const float wxv = wx##SLOT;                                            \
        { int tl = tb + (TT) + 4; if (tl > T_SEQ-1) tl = T_SEQ-1;              \
          wx##SLOT = wxp[(size_t)tl * WX_T_STRIDE]; }                          \
        v4f acc = {0.f, 0.f, 0.f, 0.f};                                        \
        const v4f* hv = (const v4f*)&hbuf[CUR][0];                             \
        const v4f h0 = hv[0],  h1 = hv[1],  h2 = hv[2],  h3 = hv[3];           \
        const v4f h4 = hv[4],  h5 = hv[5],  h6 = hv[6],  h7 = hv[7];           \
        const v4f h8 = hv[8],  h9 = hv[9],  h10 = hv[10], h11 = hv[11];        \
        const v4f h12 = hv[12], h13 = hv[13], h14 = hv[14], h15 = hv[15];      \
        DOT(r0,h0)  DOT(r1,h1)  DOT(r2,h2)  DOT(r3,h3)                         \
        DOT(r4,h4)  DOT(r5,h5)  DOT(r6,h6)  DOT(r7,h7)                         \
        DOT(r8,h8)  DOT(r9,h9)  DOT(r10,h10) DOT(r11,h11)                      \
        DOT(r12,h12) DOT(r13,h13) DOT(r14,h14) DOT(r15,h15)                    \
        const float gp = ((acc.x+acc.y)+(acc.z+acc.w)) + wxv + bval;           \
        const float ev = __builtin_amdgcn_exp2f(s_coef * gp);                  \
        const float rv = __builtin_amdgcn_rcpf(1.0f + ev);                     \
        const float a  = fmaf(m_coef, rv, a_coef);                             \
        const float v1 = QXOR(a, 0xB1);  /* gate g^1 */                        \
        const float v2 = QXOR(a, 0x4E);  /* gate g^2 */                        \
        const float v3 = QXOR(a, 0x1B);  /* gate g^3 */                        \
        /* gates[j] = vals[j^g]; valid for g==0 AND g==1 via one-bit select */ \
        const float xf = isg1 ? a  : v1;                                       \
        const float xi = isg1 ? v1 : a;                                        \
        const float xz = isg1 ? v3 : v2;                                       \
        const float xo = isg1 ? v2 : v3;                                       \
        c = fmaf(xf, c, xi * xz);                                              \
        const float e2 = __builtin_amdgcn_exp2f(-2.88539008f * c);             \
        const float th = fmaf(2.0f, __builtin_amdgcn_rcpf(1.0f + e2), -1.0f);  \
        const float hval = xo * th;                                            \
        if (g == 0) hbuf[(CUR)^1][o] = hval;                                   \
        if (g < 2) { *stp = isg1 ? c : hval; stp += OUT_T_STRIDE; }            \
        LDS_BARRIER();                                                         \
    }

    for (int tb = 0; tb < T_SEQ; tb += 4) {
        STEP(0, 0, 0)
        STEP(1, 1, 1)
        STEP(2, 2, 0)
        STEP(3, 3, 1)
    }
#undef STEP
#undef DOT
}

extern "C" void kernel_launch(void* const* d_in, const int* in_sizes, int n_in,
                              void* d_out, int out_size, void* d_ws, size_t ws_size,
                              hipStream_t stream) {
    const float* Wx = (const float*)d_in[0];
    const float* s0 = (const float*)d_in[1];
    const float* R  = (const float*)d_in[2];
    const float* bb = (const float*)d_in[3];
    float* out = (float*)d_out;
    flashrnn_lstm_fwd<<<dim3(BN_), dim3(256), 0, stream>>>(Wx, s0, R, bb, out);
}

// Round 3
// 670.980 us; speedup vs baseline: 1.0062x; 1.0039x over previous
//
#include <hip/hip_runtime.h>

// LSTM forward scan: T=1024, B=16, NH=12, HD=64, NG=4 (i,f,z,o).
// One block per (b,n) chain: 192 blocks x 256 threads; tid = o*4+g.
//
// Lessons carried:
//  * raw `s_waitcnt lgkmcnt(0); s_barrier` — __syncthreads() drains vmcnt(0)
//    and kills the Wx prefetch ring.
//  * DPP quad_perm for the gate exchange (VALU, not LDS pipe).
//  * h and c stored to out straight from registers (g==0/g==1 lanes).
// Round-5 (this round) — R-residency, with self-diagnosis:
//  * Counters were bit-identical across 3 structurally different kernels
//    (VGPR=48, VALUBusy=27%, 474us). Either the benched binary is stale, or
//    R streams from L2 every step (27 TB/s = 79% of L2 ceiling) and
//    everything else hides under that latency.
//  * hbuf[2][80]: LDS_Block_Size marker 512 -> 640. If the next profile
//    still reports 512, the harness ran a stale binary.
//  * Def-pins (asm "+v" after load) + a loop-top USE-pin naming all 16 R
//    tuples as "v" inputs: forces all 64 R floats live each iteration.
//    Neither pin carries a "memory" clobber (must not fence the loads).

#define T_SEQ 1024
#define B_    16
#define NH_   12
#define HD_   64
#define NG_   4
#define BN_   (B_*NH_)                    // 192 chains
#define WX_T_STRIDE (BN_*HD_*NG_)         // 49152 floats per timestep
#define OUT_T_STRIDE (BN_*HD_)            // 12288 floats per timestep
#define OUT_S_STRIDE ((T_SEQ+1)*OUT_T_STRIDE)

typedef float v4f __attribute__((ext_vector_type(4)));

// raw workgroup barrier: orders LDS (lgkmcnt) but does NOT drain vmcnt —
// keeps the global prefetch ring in flight across steps.
#define LDS_BARRIER() asm volatile("s_waitcnt lgkmcnt(0)\n\ts_barrier" ::: "memory")

// pin: value becomes an asm output -> not rematerializable, must stay in VGPRs.
#define PIN4(x) asm volatile("" : "+v"(x))
#define PIN1(x) asm volatile("" : "+v"(x))

// intra-quad lane exchange via DPP quad_perm — pure VALU, no LDS pipe.
// 0xB1 = [1,0,3,2] (xor1), 0x4E = [2,3,0,1] (xor2), 0x1B = [3,2,1,0] (xor3)
#define QXOR(x, CTRL) \
    __int_as_float(__builtin_amdgcn_update_dpp(0, __float_as_int(x), (CTRL), 0xF, 0xF, true))

__global__ __launch_bounds__(256, 1) __attribute__((amdgpu_waves_per_eu(1)))
void flashrnn_lstm_fwd(const float* __restrict__ Wx,
                       const float* __restrict__ s0,
                       const float* __restrict__ R,
                       const float* __restrict__ bias,
                       float* __restrict__ out)
{
    const int bid = blockIdx.x;           // 0..191
    const int n   = bid % NH_;
    const int b   = bid / NH_;
    const int bn  = b*NH_ + n;
    const int tid = threadIdx.x;          // 0..255
    const int o   = tid >> 2;             // output index 0..63
    const int g   = tid & 3;              // gate 0..3 (i,f,z,o)

    // [buf][0:64) = h; 80-stride is the binary-identity marker (LDS 640 B)
    __shared__ float hbuf[2][80];

    // --- R row R[n][g][o][0:64] into 16 named 128-bit registers, pinned ---
    const v4f* Rp = (const v4f*)(R + ((size_t)((n*NG_ + g)*HD_ + o)) * HD_);
    v4f r0 = Rp[0],  r1 = Rp[1],  r2 = Rp[2],  r3 = Rp[3];
    v4f r4 = Rp[4],  r5 = Rp[5],  r6 = Rp[6],  r7 = Rp[7];
    v4f r8 = Rp[8],  r9 = Rp[9],  r10 = Rp[10], r11 = Rp[11];
    v4f r12 = Rp[12], r13 = Rp[13], r14 = Rp[14], r15 = Rp[15];
    PIN4(r0);  PIN4(r1);  PIN4(r2);  PIN4(r3);
    PIN4(r4);  PIN4(r5);  PIN4(r6);  PIN4(r7);
    PIN4(r8);  PIN4(r9);  PIN4(r10); PIN4(r11);
    PIN4(r12); PIN4(r13); PIN4(r14); PIN4(r15);

    float bval = bias[(n*NG_ + g)*HD_ + o];
    PIN1(bval);

    // c state is valid in g==0 AND g==1 lanes (operand-swap below)
    float c = s0[BN_*HD_ + bn*HD_ + o];

    // --- init h in LDS buf 0 + write t=0 output slices ---
    if (tid < 128) {
        const int d = tid & 63;
        const size_t sofs = (tid < 64) ? (size_t)0 : (size_t)OUT_S_STRIDE;
        const float v = (tid < 64) ? s0[bn*HD_ + d] : s0[BN_*HD_ + bn*HD_ + d];
        if (tid < 64) hbuf[0][d] = v;
        out[sofs + (size_t)bn*HD_ + d] = v;                           // t = 0
    }

    // per-lane store pointer: g==0 -> h plane, g==1 -> c plane, at t=1
    const bool isg1 = (g & 1) != 0;
    float* stp = out + (isg1 ? (size_t)OUT_S_STRIDE : (size_t)0)
                     + (size_t)OUT_T_STRIDE + (size_t)bn*HD_ + o;

    // unified activation: a = m * rcp(1 + exp2(s*x)) + k
    // g in {0,1,3}: sigmoid; g==2: tanh
    const float s_coef = (g == 2) ? -2.88539008f : -1.44269504f;
    const float m_coef = (g == 2) ? 2.0f : 1.0f;
    const float a_coef = (g == 2) ? -1.0f : 0.0f;

    // --- Wx prefetch ring (depth 4), named scalars ---
    const float* wxp = Wx + (size_t)bn*(HD_*NG_) + tid;
    float wx0 = wxp[0];
    float wx1 = wxp[(size_t)1 * WX_T_STRIDE];
    float wx2 = wxp[(size_t)2 * WX_T_STRIDE];
    float wx3 = wxp[(size_t)3 * WX_T_STRIDE];

    __syncthreads();   // one full barrier before the loop (drains init loads)

#define DOT(R4, H4)                                                            \
        acc.x = fmaf((R4).x, (H4).x, acc.x);                                   \
        acc.y = fmaf((R4).y, (H4).y, acc.y);                                   \
        acc.z = fmaf((R4).z, (H4).z, acc.z);                                   \
        acc.w = fmaf((R4).w, (H4).w, acc.w);

#define STEP(TT, SLOT, CUR)                                                    \
    {                                                                          \
        /* USE-pin: all 16 R tuples (64 VGPRs) forced live this iteration */   \
        asm volatile("" :: "v"(r0), "v"(r1), "v"(r2),  "v"(r3),                \
                           "v"(r4), "v"(r5), "v"(r6),  "v"(r7),                \
                           "v"(r8), "v"(r9), "v"(r10), "v"(r11),               \
                           "v"(r12),"v"(r13),"v"(r14), "v"(r15));              \
        const float wxv = wx##SLOT;                                            \
        { int tl = tb + (TT) + 4; if (tl > T_SEQ-1) tl = T_SEQ-1;              \
          wx##SLOT = wxp[(size_t)tl * WX_T_STRIDE]; }                          \
        v4f acc = {0.f, 0.f, 0.f, 0.f};                                        \
        const v4f* hv = (const v4f*)&hbuf[CUR][0];                             \
        const v4f h0 = hv[0],  h1 = hv[1],  h2 = hv[2],  h3 = hv[3];           \
        const v4f h4 = hv[4],  h5 = hv[5],  h6 = hv[6],  h7 = hv[7];           \
        const v4f h8 = hv[8],  h9 = hv[9],  h10 = hv[10], h11 = hv[11];        \
        const v4f h12 = hv[12], h13 = hv[13], h14 = hv[14], h15 = hv[15];      \
        DOT(r0,h0)  DOT(r1,h1)  DOT(r2,h2)  DOT(r3,h3)                         \
        DOT(r4,h4)  DOT(r5,h5)  DOT(r6,h6)  DOT(r7,h7)                         \
        DOT(r8,h8)  DOT(r9,h9)  DOT(r10,h10) DOT(r11,h11)                      \
        DOT(r12,h12) DOT(r13,h13) DOT(r14,h14) DOT(r15,h15)                    \
        const float gp = ((acc.x+acc.y)+(acc.z+acc.w)) + wxv + bval;           \
        const float ev = __builtin_amdgcn_exp2f(s_coef * gp);                  \
        const float rv = __builtin_amdgcn_rcpf(1.0f + ev);                     \
        const float a  = fmaf(m_coef, rv, a_coef);                             \
        const float v1 = QXOR(a, 0xB1);  /* gate g^1 */                        \
        const float v2 = QXOR(a, 0x4E);  /* gate g^2 */                        \
        const float v3 = QXOR(a, 0x1B);  /* gate g^3 */                        \
        /* gates[j] = vals[j^g]; valid for g==0 AND g==1 via one-bit select */ \
        const float xf = isg1 ? a  : v1;                                       \
        const float xi = isg1 ? v1 : a;                                        \
        const float xz = isg1 ? v3 : v2;                                       \
        const float xo = isg1 ? v2 : v3;                                       \
        c = fmaf(xf, c, xi * xz);                                              \
        const float e2 = __builtin_amdgcn_exp2f(-2.88539008f * c);             \
        const float th = fmaf(2.0f, __builtin_amdgcn_rcpf(1.0f + e2), -1.0f);  \
        const float hval = xo * th;                                            \
        if (g == 0) hbuf[(CUR)^1][o] = hval;                                   \
        if (g < 2) { *stp = isg1 ? c : hval; stp += OUT_T_STRIDE; }            \
        LDS_BARRIER();                                                         \
    }

    for (int tb = 0; tb < T_SEQ; tb += 4) {
        STEP(0, 0, 0)
        STEP(1, 1, 1)
        STEP(2, 2, 0)
        STEP(3, 3, 1)
    }
#undef STEP
#undef DOT
}

extern "C" void kernel_launch(void* const* d_in, const int* in_sizes, int n_in,
                              void* d_out, int out_size, void* d_ws, size_t ws_size,
                              hipStream_t stream) {
    const float* Wx = (const float*)d_in[0];
    const float* s0 = (const float*)d_in[1];
    const float* R  = (const float*)d_in[2];
    const float* bb = (const float*)d_in[3];
    float* out = (float*)d_out;
    flashrnn_lstm_fwd<<<dim3(BN_), dim3(256), 0, stream>>>(Wx, s0, R, bb, out);
}

// Round 4
// 583.837 us; speedup vs baseline: 1.1564x; 1.1493x over previous
//
#include <hip/hip_runtime.h>

// LSTM forward scan: T=1024, B=16, NH=12, HD=64, NG=4 (i,f,z,o).
// One block per (b,n) chain: 192 blocks x 256 threads; tid = o*4+g.
//
// Lessons carried:
//  * raw `s_waitcnt lgkmcnt(0); s_barrier` — __syncthreads() drains vmcnt(0)
//    and kills the Wx prefetch ring.
//  * DPP quad_perm for all intra-quad exchanges (VALU, not LDS pipe).
//  * h and c stored to out straight from registers (g==0/g==1 lanes).
//  * R pinned via asm (lands in unified VGPR/AGPR file; VGPR_Count=48 is
//    arch-VGPRs only — R residency confirmed NOT the bottleneck in R2).
// Round-6 (this round) — quad-split dot to unload the LDS pipe:
//  * Old: every lane read all 64 h floats => 64 ds_read_b128/CU/step
//    = 64 KB/step of LDS->VGPR fill (>=256cyc floor, ~768cyc practical)
//    — the shared cost all identical-timing variants had in common.
//  * New: lane (o,g) accumulates ALL 4 gates over h[16g:16g+16) only
//    (4 ds_read_b128/lane -> 16/CU/step, 16x less LDS return traffic).
//    R rows loaded xor-permuted (accumulator m holds gate g^m) so a
//    2-hop DPP butterfly with compile-time indices reduces partials;
//    only own-gate dot is materialized: 3 DPP-adds total.
//    Tail (activation, gate exchange, selects, stores) unchanged.

#define T_SEQ 1024
#define B_    16
#define NH_   12
#define HD_   64
#define NG_   4
#define BN_   (B_*NH_)                    // 192 chains
#define WX_T_STRIDE (BN_*HD_*NG_)         // 49152 floats per timestep
#define OUT_T_STRIDE (BN_*HD_)            // 12288 floats per timestep
#define OUT_S_STRIDE ((T_SEQ+1)*OUT_T_STRIDE)

typedef float v4f __attribute__((ext_vector_type(4)));

// raw workgroup barrier: orders LDS (lgkmcnt) but does NOT drain vmcnt —
// keeps the global prefetch ring in flight across steps.
#define LDS_BARRIER() asm volatile("s_waitcnt lgkmcnt(0)\n\ts_barrier" ::: "memory")

// pin: value becomes an asm output -> not rematerializable.
#define PIN4(x) asm volatile("" : "+v"(x))
#define PIN1(x) asm volatile("" : "+v"(x))

// intra-quad lane exchange via DPP quad_perm — pure VALU, no LDS pipe.
// 0xB1 = [1,0,3,2] (xor1), 0x4E = [2,3,0,1] (xor2), 0x1B = [3,2,1,0] (xor3)
#define QXOR(x, CTRL) \
    __int_as_float(__builtin_amdgcn_update_dpp(0, __float_as_int(x), (CTRL), 0xF, 0xF, true))

__device__ __forceinline__ float dot16(v4f a0, v4f a1, v4f a2, v4f a3,
                                       v4f h0, v4f h1, v4f h2, v4f h3)
{
    float p = a0.x * h0.x;
    p = fmaf(a0.y, h0.y, p); p = fmaf(a0.z, h0.z, p); p = fmaf(a0.w, h0.w, p);
    p = fmaf(a1.x, h1.x, p); p = fmaf(a1.y, h1.y, p);
    p = fmaf(a1.z, h1.z, p); p = fmaf(a1.w, h1.w, p);
    p = fmaf(a2.x, h2.x, p); p = fmaf(a2.y, h2.y, p);
    p = fmaf(a2.z, h2.z, p); p = fmaf(a2.w, h2.w, p);
    p = fmaf(a3.x, h3.x, p); p = fmaf(a3.y, h3.y, p);
    p = fmaf(a3.z, h3.z, p); p = fmaf(a3.w, h3.w, p);
    return p;
}

__global__ __launch_bounds__(256, 1) __attribute__((amdgpu_waves_per_eu(1)))
void flashrnn_lstm_fwd(const float* __restrict__ Wx,
                       const float* __restrict__ s0,
                       const float* __restrict__ R,
                       const float* __restrict__ bias,
                       float* __restrict__ out)
{
    const int bid = blockIdx.x;           // 0..191
    const int n   = bid % NH_;
    const int b   = bid / NH_;
    const int bn  = b*NH_ + n;
    const int tid = threadIdx.x;          // 0..255
    const int o   = tid >> 2;             // output index 0..63
    const int g   = tid & 3;              // gate 0..3 (i,f,z,o)

    // [buf][0:64) = h; 80-stride keeps rows 16B-aligned (320 B) + marker
    __shared__ __align__(16) float hbuf[2][80];

    // --- R slices: accumulator m holds gate (g^m), columns [16g, 16g+16) ---
    const size_t rowstride = (size_t)HD_*HD_;
    const float* Rh = R + (size_t)n*NG_*rowstride + (size_t)o*HD_ + g*16;
    const v4f* RpA = (const v4f*)(Rh + (size_t)(g^0)*rowstride);
    const v4f* RpB = (const v4f*)(Rh + (size_t)(g^1)*rowstride);
    const v4f* RpC = (const v4f*)(Rh + (size_t)(g^2)*rowstride);
    const v4f* RpD = (const v4f*)(Rh + (size_t)(g^3)*rowstride);
    v4f r00 = RpA[0], r01 = RpA[1], r02 = RpA[2], r03 = RpA[3];
    v4f r10 = RpB[0], r11 = RpB[1], r12 = RpB[2], r13 = RpB[3];
    v4f r20 = RpC[0], r21 = RpC[1], r22 = RpC[2], r23 = RpC[3];
    v4f r30 = RpD[0], r31 = RpD[1], r32 = RpD[2], r33 = RpD[3];
    PIN4(r00); PIN4(r01); PIN4(r02); PIN4(r03);
    PIN4(r10); PIN4(r11); PIN4(r12); PIN4(r13);
    PIN4(r20); PIN4(r21); PIN4(r22); PIN4(r23);
    PIN4(r30); PIN4(r31); PIN4(r32); PIN4(r33);

    float bval = bias[(n*NG_ + g)*HD_ + o];
    PIN1(bval);

    // c state is valid in g==0 AND g==1 lanes (operand-swap below)
    float c = s0[BN_*HD_ + bn*HD_ + o];

    // --- init h in LDS buf 0 + write t=0 output slices ---
    if (tid < 128) {
        const int d = tid & 63;
        const size_t sofs = (tid < 64) ? (size_t)0 : (size_t)OUT_S_STRIDE;
        const float v = (tid < 64) ? s0[bn*HD_ + d] : s0[BN_*HD_ + bn*HD_ + d];
        if (tid < 64) hbuf[0][d] = v;
        out[sofs + (size_t)bn*HD_ + d] = v;                           // t = 0
    }

    // per-lane store pointer: g==0 -> h plane, g==1 -> c plane, at t=1
    const bool isg1 = (g & 1) != 0;
    float* stp = out + (isg1 ? (size_t)OUT_S_STRIDE : (size_t)0)
                     + (size_t)OUT_T_STRIDE + (size_t)bn*HD_ + o;

    // unified activation: a = m * rcp(1 + exp2(s*x)) + k
    // g in {0,1,3}: sigmoid; g==2: tanh
    const float s_coef = (g == 2) ? -2.88539008f : -1.44269504f;
    const float m_coef = (g == 2) ? 2.0f : 1.0f;
    const float a_coef = (g == 2) ? -1.0f : 0.0f;

    // --- Wx prefetch ring (depth 4), named scalars ---
    const float* wxp = Wx + (size_t)bn*(HD_*NG_) + tid;
    float wx0 = wxp[0];
    float wx1 = wxp[(size_t)1 * WX_T_STRIDE];
    float wx2 = wxp[(size_t)2 * WX_T_STRIDE];
    float wx3 = wxp[(size_t)3 * WX_T_STRIDE];

    __syncthreads();   // one full barrier before the loop (drains init loads)

#define STEP(TT, SLOT, CUR)                                                    \
    {                                                                          \
        /* USE-pin: all 16 R tuples forced live this iteration */              \
        asm volatile("" :: "v"(r00), "v"(r01), "v"(r02), "v"(r03),             \
                           "v"(r10), "v"(r11), "v"(r12), "v"(r13),             \
                           "v"(r20), "v"(r21), "v"(r22), "v"(r23),             \
                           "v"(r30), "v"(r31), "v"(r32), "v"(r33));            \
        const float wxv = wx##SLOT;                                            \
        { int tl = tb + (TT) + 4; if (tl > T_SEQ-1) tl = T_SEQ-1;              \
          wx##SLOT = wxp[(size_t)tl * WX_T_STRIDE]; }                          \
        /* quarter-h: lane (o,g) reads h[16g : 16g+16) — 4 x ds_read_b128 */   \
        const v4f* hv = (const v4f*)&hbuf[CUR][g*16];                          \
        const v4f ha = hv[0], hb = hv[1], hcq = hv[2], hd = hv[3];             \
        /* partial dots: p_m = gate (g^m) over this lane's 16 columns */       \
        float p0 = dot16(r00, r01, r02, r03, ha, hb, hcq, hd);                 \
        float p1 = dot16(r10, r11, r12, r13, ha, hb, hcq, hd);                 \
        float p2 = dot16(r20, r21, r22, r23, ha, hb, hcq, hd);                 \
        float p3 = dot16(r30, r31, r32, r33, ha, hb, hcq, hd);                 \
        /* quad butterfly (own gate only): */                                  \
        /* q0 = own-gate sum over cols of (g, g^1); q2 = same for gate g */    \
        const float q0 = p0 + QXOR(p1, 0xB1);                                  \
        const float q2 = p2 + QXOR(p3, 0xB1);                                  \
        const float d0 = q0 + QXOR(q2, 0x4E);   /* full dot, own gate */       \
        const float gp = d0 + wxv + bval;                                      \
        const float ev = __builtin_amdgcn_exp2f(s_coef * gp);                  \
        const float rv = __builtin_amdgcn_rcpf(1.0f + ev);                     \
        const float a  = fmaf(m_coef, rv, a_coef);                             \
        const float v1 = QXOR(a, 0xB1);  /* gate g^1 */                        \
        const float v2 = QXOR(a, 0x4E);  /* gate g^2 */                        \
        const float v3 = QXOR(a, 0x1B);  /* gate g^3 */                        \
        /* gates[j] = vals[j^g]; valid for g==0 AND g==1 via one-bit select */ \
        const float xf = isg1 ? a  : v1;                                       \
        const float xi = isg1 ? v1 : a;                                        \
        const float xz = isg1 ? v3 : v2;                                       \
        const float xo = isg1 ? v2 : v3;                                       \
        c = fmaf(xf, c, xi * xz);                                              \
        const float e2 = __builtin_amdgcn_exp2f(-2.88539008f * c);             \
        const float th = fmaf(2.0f, __builtin_amdgcn_rcpf(1.0f + e2), -1.0f);  \
        const float hval = xo * th;                                            \
        if (g == 0) hbuf[(CUR)^1][o] = hval;                                   \
        if (g < 2) { *stp = isg1 ? c : hval; stp += OUT_T_STRIDE; }            \
        LDS_BARRIER();                                                         \
    }

    for (int tb = 0; tb < T_SEQ; tb += 4) {
        STEP(0, 0, 0)
        STEP(1, 1, 1)
        STEP(2, 2, 0)
        STEP(3, 3, 1)
    }
#undef STEP
}

extern "C" void kernel_launch(void* const* d_in, const int* in_sizes, int n_in,
                              void* d_out, int out_size, void* d_ws, size_t ws_size,
                              hipStream_t stream) {
    const float* Wx = (const float*)d_in[0];
    const float* s0 = (const float*)d_in[1];
    const float* R  = (const float*)d_in[2];
    const float* bb = (const float*)d_in[3];
    float* out = (float*)d_out;
    flashrnn_lstm_fwd<<<dim3(BN_), dim3(256), 0, stream>>>(Wx, s0, R, bb, out);
}

// Round 5
// 571.882 us; speedup vs baseline: 1.1806x; 1.0209x over previous
//
#include <hip/hip_runtime.h>

// LSTM forward scan: T=1024, B=16, NH=12, HD=64, NG=4 (i,f,z,o).
// One block per (b,n) chain: 192 blocks x 256 threads; tid = o*4+g.
//
// Lessons carried:
//  * raw `s_waitcnt lgkmcnt(0); s_barrier` — __syncthreads() drains vmcnt(0)
//    and kills the Wx prefetch ring.
//  * DPP quad_perm for all intra-quad exchanges (VALU, not LDS pipe).
//  * Quad-split dot (R4: 474->382us): lane (o,g) dots all 4 gates over
//    h[16g:16g+16); 2-hop DPP butterfly combines. 16x less LDS traffic.
//  * R pinned via asm; FMA issue floor = 128 cyc/step (invariant).
// Round-7 (this round) — reclaim scheduling slack on the serial chain:
//  * ds_reads issue FIRST after barrier (addr math was delaying them).
//  * global stores software-pipelined: step stores PREVIOUS step's (h,c)
//    from registers inside the LDS-read latency shadow, not after hval.
//  * prefetch = 4 walking pointers, no per-step mul/clamp; clamp-free
//    main loop (prefetch idx <= 1023 by construction) + 4-step epilogue.
//  * USE-pin hoisted to once per 4-step iteration; last step skips
//    hbuf write + barrier; final store after loop.

#define T_SEQ 1024
#define B_    16
#define NH_   12
#define HD_   64
#define NG_   4
#define BN_   (B_*NH_)                    // 192 chains
#define WX_T_STRIDE (BN_*HD_*NG_)         // 49152 floats per timestep
#define OUT_T_STRIDE (BN_*HD_)            // 12288 floats per timestep
#define OUT_S_STRIDE ((T_SEQ+1)*OUT_T_STRIDE)

typedef float v4f __attribute__((ext_vector_type(4)));

// raw workgroup barrier: orders LDS (lgkmcnt) but does NOT drain vmcnt —
// keeps the global prefetch ring in flight across steps.
#define LDS_BARRIER() asm volatile("s_waitcnt lgkmcnt(0)\n\ts_barrier" ::: "memory")

// pin: value becomes an asm output -> not rematerializable.
#define PIN4(x) asm volatile("" : "+v"(x))
#define PIN1(x) asm volatile("" : "+v"(x))

// intra-quad lane exchange via DPP quad_perm — pure VALU, no LDS pipe.
// 0xB1 = [1,0,3,2] (xor1), 0x4E = [2,3,0,1] (xor2), 0x1B = [3,2,1,0] (xor3)
#define QXOR(x, CTRL) \
    __int_as_float(__builtin_amdgcn_update_dpp(0, __float_as_int(x), (CTRL), 0xF, 0xF, true))

__device__ __forceinline__ float dot16(v4f a0, v4f a1, v4f a2, v4f a3,
                                       v4f h0, v4f h1, v4f h2, v4f h3)
{
    float p = a0.x * h0.x;
    p = fmaf(a0.y, h0.y, p); p = fmaf(a0.z, h0.z, p); p = fmaf(a0.w, h0.w, p);
    p = fmaf(a1.x, h1.x, p); p = fmaf(a1.y, h1.y, p);
    p = fmaf(a1.z, h1.z, p); p = fmaf(a1.w, h1.w, p);
    p = fmaf(a2.x, h2.x, p); p = fmaf(a2.y, h2.y, p);
    p = fmaf(a2.z, h2.z, p); p = fmaf(a2.w, h2.w, p);
    p = fmaf(a3.x, h3.x, p); p = fmaf(a3.y, h3.y, p);
    p = fmaf(a3.z, h3.z, p); p = fmaf(a3.w, h3.w, p);
    return p;
}

__global__ __launch_bounds__(256, 1) __attribute__((amdgpu_waves_per_eu(1)))
void flashrnn_lstm_fwd(const float* __restrict__ Wx,
                       const float* __restrict__ s0,
                       const float* __restrict__ R,
                       const float* __restrict__ bias,
                       float* __restrict__ out)
{
    const int bid = blockIdx.x;           // 0..191
    const int n   = bid % NH_;
    const int b   = bid / NH_;
    const int bn  = b*NH_ + n;
    const int tid = threadIdx.x;          // 0..255
    const int o   = tid >> 2;             // output index 0..63
    const int g   = tid & 3;              // gate 0..3 (i,f,z,o)

    // [buf][0:64) = h; 80-stride keeps rows 16B-aligned + build marker
    __shared__ __align__(16) float hbuf[2][80];

    // --- R slices: accumulator m holds gate (g^m), columns [16g, 16g+16) ---
    const size_t rowstride = (size_t)HD_*HD_;
    const float* Rh = R + (size_t)n*NG_*rowstride + (size_t)o*HD_ + g*16;
    const v4f* RpA = (const v4f*)(Rh + (size_t)(g^0)*rowstride);
    const v4f* RpB = (const v4f*)(Rh + (size_t)(g^1)*rowstride);
    const v4f* RpC = (const v4f*)(Rh + (size_t)(g^2)*rowstride);
    const v4f* RpD = (const v4f*)(Rh + (size_t)(g^3)*rowstride);
    v4f r00 = RpA[0], r01 = RpA[1], r02 = RpA[2], r03 = RpA[3];
    v4f r10 = RpB[0], r11 = RpB[1], r12 = RpB[2], r13 = RpB[3];
    v4f r20 = RpC[0], r21 = RpC[1], r22 = RpC[2], r23 = RpC[3];
    v4f r30 = RpD[0], r31 = RpD[1], r32 = RpD[2], r33 = RpD[3];
    PIN4(r00); PIN4(r01); PIN4(r02); PIN4(r03);
    PIN4(r10); PIN4(r11); PIN4(r12); PIN4(r13);
    PIN4(r20); PIN4(r21); PIN4(r22); PIN4(r23);
    PIN4(r30); PIN4(r31); PIN4(r32); PIN4(r33);

    float bval = bias[(n*NG_ + g)*HD_ + o];
    PIN1(bval);

    // c state is valid in g==0 AND g==1 lanes (operand-swap below)
    float c = s0[BN_*HD_ + bn*HD_ + o];

    // --- init h in LDS buf 0 ---
    if (tid < 64) hbuf[0][tid] = s0[bn*HD_ + tid];

    // hoisted LDS pointers (compile-time selected per step parity)
    const v4f* hv0 = (const v4f*)&hbuf[0][g*16];
    const v4f* hv1 = (const v4f*)&hbuf[1][g*16];
    float* hw0 = &hbuf[1][o];             // CUR=0 writes buf1
    float* hw1 = &hbuf[0][o];             // CUR=1 writes buf0

    // software-pipelined output store: sv holds the value for row t, stored
    // at the TOP of the step computing t+1 (inside the LDS-read shadow).
    const bool isg1 = (g & 1) != 0;
    float sv = isg1 ? c : s0[bn*HD_ + o];               // t = 0 state
    float* stp = out + (isg1 ? (size_t)OUT_S_STRIDE : (size_t)0)
                     + (size_t)bn*HD_ + o;              // t = 0 row

    // unified activation: a = m * rcp(1 + exp2(s*x)) + k
    // g in {0,1,3}: sigmoid; g==2: tanh
    const float s_coef = (g == 2) ? -2.88539008f : -1.44269504f;
    const float m_coef = (g == 2) ? 2.0f : 1.0f;
    const float a_coef = (g == 2) ? -1.0f : 0.0f;

    // --- Wx prefetch ring (depth 4) + walking prefetch pointers ---
    const float* wxp = Wx + (size_t)bn*(HD_*NG_) + tid;
    float wx0 = wxp[0];
    float wx1 = wxp[(size_t)1 * WX_T_STRIDE];
    float wx2 = wxp[(size_t)2 * WX_T_STRIDE];
    float wx3 = wxp[(size_t)3 * WX_T_STRIDE];
    const float* wp0 = wxp + (size_t)4 * WX_T_STRIDE;
    const float* wp1 = wxp + (size_t)5 * WX_T_STRIDE;
    const float* wp2 = wxp + (size_t)6 * WX_T_STRIDE;
    const float* wp3 = wxp + (size_t)7 * WX_T_STRIDE;

    __syncthreads();   // one full barrier before the loop (drains init loads)

// COMPUTE = dots + butterfly + activation + state update (bit-identical R4)
#define COMPUTE(HA, HB, HC, HD4, WXV)                                          \
        float p0 = dot16(r00, r01, r02, r03, HA, HB, HC, HD4);                 \
        float p1 = dot16(r10, r11, r12, r13, HA, HB, HC, HD4);                 \
        float p2 = dot16(r20, r21, r22, r23, HA, HB, HC, HD4);                 \
        float p3 = dot16(r30, r31, r32, r33, HA, HB, HC, HD4);                 \
        const float q0 = p0 + QXOR(p1, 0xB1);                                  \
        const float q2 = p2 + QXOR(p3, 0xB1);                                  \
        const float d0 = q0 + QXOR(q2, 0x4E);   /* full dot, own gate */       \
        const float gp = d0 + (WXV) + bval;                                    \
        const float ev = __builtin_amdgcn_exp2f(s_coef * gp);                  \
        const float rv = __builtin_amdgcn_rcpf(1.0f + ev);                     \
        const float a  = fmaf(m_coef, rv, a_coef);                             \
        const float v1 = QXOR(a, 0xB1);  /* gate g^1 */                        \
        const float v2 = QXOR(a, 0x4E);  /* gate g^2 */                        \
        const float v3 = QXOR(a, 0x1B);  /* gate g^3 */                        \
        const float xf = isg1 ? a  : v1;                                       \
        const float xi = isg1 ? v1 : a;                                        \
        const float xz = isg1 ? v3 : v2;                                       \
        const float xo = isg1 ? v2 : v3;                                       \
        c = fmaf(xf, c, xi * xz);                                              \
        const float e2 = __builtin_amdgcn_exp2f(-2.88539008f * c);             \
        const float th = fmaf(2.0f, __builtin_amdgcn_rcpf(1.0f + e2), -1.0f);  \
        const float hval = xo * th;                                            \
        sv = isg1 ? c : hval;

// main-loop step: reads first, prev-store + prefetch in the read shadow
#define STEP(SLOT, CUR)                                                        \
    {                                                                          \
        const v4f* hv = (CUR) ? hv1 : hv0;                                     \
        const v4f ha = hv[0], hb = hv[1], hcq = hv[2], hd4 = hv[3];            \
        if (g < 2) { *stp = sv; stp += OUT_T_STRIDE; }                         \
        const float wxv = wx##SLOT;                                            \
        wx##SLOT = *wp##SLOT;                                                  \
        wp##SLOT += (size_t)4 * WX_T_STRIDE;                                   \
        COMPUTE(ha, hb, hcq, hd4, wxv)                                         \
        if (g == 0) *((CUR) ? hw1 : hw0) = hval;                               \
        LDS_BARRIER();                                                         \
    }

// epilogue step: no prefetch; LAST skips hbuf write + barrier
#define STEPE(SLOT, CUR, LAST)                                                 \
    {                                                                          \
        const v4f* hv = (CUR) ? hv1 : hv0;                                     \
        const v4f ha = hv[0], hb = hv[1], hcq = hv[2], hd4 = hv[3];            \
        if (g < 2) { *stp = sv; stp += OUT_T_STRIDE; }                         \
        const float wxv = wx##SLOT;                                            \
        COMPUTE(ha, hb, hcq, hd4, wxv)                                         \
        if (!(LAST)) {                                                         \
            if (g == 0) *((CUR) ? hw1 : hw0) = hval;                           \
            LDS_BARRIER();                                                     \
        }                                                                      \
    }

    for (int tb = 0; tb < T_SEQ-4; tb += 4) {
        // USE-pin: all 16 R tuples forced live, once per 4-step iteration
        asm volatile("" :: "v"(r00), "v"(r01), "v"(r02), "v"(r03),
                           "v"(r10), "v"(r11), "v"(r12), "v"(r13),
                           "v"(r20), "v"(r21), "v"(r22), "v"(r23),
                           "v"(r30), "v"(r31), "v"(r32), "v"(r33));
        STEP(0, 0)
        STEP(1, 1)
        STEP(2, 0)
        STEP(3, 1)
    }
    // epilogue: t = 1021..1024, consuming wx0..wx3 (= Wx[1020..1023])
    STEPE(0, 0, 0)
    STEPE(1, 1, 0)
    STEPE(2, 0, 0)
    STEPE(3, 1, 1)

    // final store: t = T_SEQ row
    if (g < 2) *stp = sv;

#undef STEP
#undef STEPE
#undef COMPUTE
}

extern "C" void kernel_launch(void* const* d_in, const int* in_sizes, int n_in,
                              void* d_out, int out_size, void* d_ws, size_t ws_size,
                              hipStream_t stream) {
    const float* Wx = (const float*)d_in[0];
    const float* s0 = (const float*)d_in[1];
    const float* R  = (const float*)d_in[2];
    const float* bb = (const float*)d_in[3];
    float* out = (float*)d_out;
    flashrnn_lstm_fwd<<<dim3(BN_), dim3(256), 0, stream>>>(Wx, s0, R, bb, out);
}